// Round 19
// baseline (75.308 us; speedup 1.0000x reference)
//
#include <hip/hip_runtime.h>
#include <hip/hip_bf16.h>

#define MB 2
#define NQ 1024
#define NK 1024
#define DXC 256
#define HD 256
#define HH 8
#define DD 32
#define KHC 32
#define LOG2E 1.4426950408889634f
#define QSCALE 0.25503472301046627f   // 32^-0.5 * LOG2E

#define QB 16
#define KB 32
#define KSPLIT 8
#define KL 128
#define NCHUNK 4

// ws layout (float offsets)
#define QPB_F   0u            // bf16 q (scaled QSCALE)  [2][1024][256]
#define KPB_F   262144u       // bf16 k
#define VPT_F   524288u       // bf16 v^T [2][256][1024]
#define WT_F    786432u       // bf16 W^T x4 mats [4][256 col][256 k]
#define AQH_F   917504u       // f16 aq [2][1024][32]
#define BKH_F   950272u       // f16 bk [2][1024][32]
#define TS_F    983040u       // f32 tsum[4] (+pad to 8)
#define TKX_F   983048u       // bf16 [2][3][1024] (tk0,tk1,ones)
#define W2T_F   986120u       // f16 [16][32] Wk2^T*LOG2E
#define PART_F  986376u       // ushort [16mh][8ks][1024q][40]

typedef float f32x4 __attribute__((ext_vector_type(4)));
typedef short bf16x8 __attribute__((ext_vector_type(8)));
typedef _Float16 f16x8 __attribute__((ext_vector_type(8)));
typedef _Float16 f16x2 __attribute__((ext_vector_type(2)));

#define MFMA(a, b, c)   __builtin_amdgcn_mfma_f32_16x16x32_bf16(a, b, c, 0, 0, 0)
#define MFMA16(a, b, c) __builtin_amdgcn_mfma_f32_16x16x32_f16(a, b, c, 0, 0, 0)
#define EXP2(x) exp2f(x)

// sKD geometry (QB=16): [h][q][k] f16, k-stride 36, plane stride 584 shorts
#define KDQ 36
#define KDH2 584

struct Ptrs {
    const float *xq, *xk, *xv, *tq, *tk;
    const float *Wq, *Wk, *Wv, *Wo, *bo;
    const float *Wk1, *bk1, *Wk2, *bk2, *Wphi, *bphi;
    float* wsf;
    float* out;
};

__device__ __forceinline__ uint cvt_pk_bf16(float lo, float hi) {
    uint r;
    asm("v_cvt_pk_bf16_f32 %0, %1, %2" : "=v"(r) : "v"(lo), "v"(hi));
    return r;
}
__device__ __forceinline__ ushort f2bf1(float f) { return (ushort)cvt_pk_bf16(f, 0.f); }
__device__ __forceinline__ float bf2f(uint x) {
    return __uint_as_float((x & 0xffffu) << 16);
}
__device__ __forceinline__ ushort f2h(float f) {
    _Float16 h = (_Float16)f;
    return __builtin_bit_cast(ushort, h);
}

// ===================== KERNEL A: wconv (64 blocks) ==========================
__global__ __launch_bounds__(256, 4) void k_wconv(Ptrs p) {
    __shared__ __align__(16) float sW[64][65];
    const int u = blockIdx.x;
    const int t = threadIdx.x;
    ushort* wt = (ushort*)(p.wsf + WT_F);

    const int mat = u >> 4;
    const float* W = (mat == 0) ? p.Wq : (mat == 1) ? p.Wk : (mat == 2) ? p.Wv : p.Wo;
    const int k0 = (u & 3) * 64, c0 = ((u >> 2) & 3) * 64;
    #pragma unroll
    for (int i = 0; i < 4; ++i) {
        int flat = i * 1024 + t * 4;
        int r = flat >> 6, c = flat & 63;
        float4 v4 = *(const float4*)(W + (size_t)(k0 + r) * 256 + c0 + c);
        sW[r][c] = v4.x; sW[r][c + 1] = v4.y; sW[r][c + 2] = v4.z; sW[r][c + 3] = v4.w;
    }
    __syncthreads();
    #pragma unroll
    for (int i = 0; i < 4; ++i) {
        int flat = i * 1024 + t * 4;
        int cc = flat >> 6, kk = flat & 63;
        uint2 pk;
        pk.x = cvt_pk_bf16(sW[kk][cc], sW[kk + 1][cc]);
        pk.y = cvt_pk_bf16(sW[kk + 2][cc], sW[kk + 3][cc]);
        *(uint2*)(wt + (size_t)mat * 65536 + (size_t)(c0 + cc) * 256 + k0 + kk) = pk;
    }
}

// ===================== KERNEL B: projections + prep (667 blocks) ============
__global__ __launch_bounds__(256, 4) void k_projprep(Ptrs p) {
    __shared__ __align__(16) ushort sTr[256][24];
    const int u = blockIdx.x;
    const int t = threadIdx.x;
    ushort* qpb = (ushort*)(p.wsf + QPB_F);
    ushort* kpb = (ushort*)(p.wsf + KPB_F);
    ushort* vpt = (ushort*)(p.wsf + VPT_F);
    const ushort* wt = (const ushort*)(p.wsf + WT_F);
    ushort* aqh = (ushort*)(p.wsf + AQH_F);
    ushort* bkh = (ushort*)(p.wsf + BKH_F);
    ushort* tkx = (ushort*)(p.wsf + TKX_F);
    ushort* w2t = (ushort*)(p.wsf + W2T_F);
    float*  ts  = p.wsf + TS_F;

    if (u < 384) {
        // ---- projections ----
        const int z = u / 128;            // 0=q, 1=k, 2=v
        const int R0 = (u % 128) * 16;    // row in [0, 2048)
        const float* x = (z == 0) ? p.xq : (z == 1) ? p.xk : p.xv;
        const ushort* wz = wt + (size_t)z * 65536;
        const int wid = t >> 6, l = t & 63, g = l >> 4, c16 = l & 15;
        const int wc = wid * 64;
        const int row = R0 + c16;

        f32x4 acc[4];
        #pragma unroll
        for (int i = 0; i < 4; ++i) acc[i] = (f32x4){0.f, 0.f, 0.f, 0.f};

        for (int k0 = 0; k0 < DXC; k0 += 32) {
            const float* xr = x + (size_t)row * DXC + k0 + g * 8;
            float4 a0 = *(const float4*)xr;
            float4 a1 = *(const float4*)(xr + 4);
            union { bf16x8 v; uint d[4]; } af;
            af.d[0] = cvt_pk_bf16(a0.x, a0.y);
            af.d[1] = cvt_pk_bf16(a0.z, a0.w);
            af.d[2] = cvt_pk_bf16(a1.x, a1.y);
            af.d[3] = cvt_pk_bf16(a1.z, a1.w);
            #pragma unroll
            for (int cf = 0; cf < 4; ++cf) {
                bf16x8 bf = *(const bf16x8*)(wz + (size_t)(wc + cf * 16 + c16) * 256 + k0 + g * 8);
                acc[cf] = MFMA(af.v, bf, acc[cf]);
            }
        }
        if (z != 2) {
            #pragma unroll
            for (int cf = 0; cf < 4; ++cf) {
                #pragma unroll
                for (int r = 0; r < 4; ++r) {
                    int orow = R0 + g * 4 + r;
                    int col = wc + cf * 16 + c16;
                    float v = acc[cf][r];
                    if (z == 0) qpb[(size_t)orow * HD + col] = f2bf1(v * QSCALE);
                    else        kpb[(size_t)orow * HD + col] = f2bf1(v);
                }
            }
        } else {
            #pragma unroll
            for (int cf = 0; cf < 4; ++cf)
                #pragma unroll
                for (int r = 0; r < 4; ++r)
                    sTr[wc + cf * 16 + c16][g * 4 + r] = f2bf1(acc[cf][r]);
            __syncthreads();
            const int mq = R0 >> 10, rin = R0 & 1023;
            ushort* dst = vpt + (size_t)mq * (HD * NK) + (size_t)t * NK + rin;
            *(uint4*)dst       = *(const uint4*)&sTr[t][0];
            *(uint4*)(dst + 8) = *(const uint4*)&sTr[t][8];
        }
    } else if (u < 640) {
        int gid = (u - 384) * 256 + t;    // 0..65535
        int row = gid >> 5, j = gid & 31;
        aqh[gid] = f2h(p.tq[row * 2] * p.Wk1[j] + p.tq[row * 2 + 1] * p.Wk1[KHC + j] + p.bk1[j]);
        bkh[gid] = f2h(p.tk[row * 2] * p.Wk1[j] + p.tk[row * 2 + 1] * p.Wk1[KHC + j]);
    } else if (u < 664) {
        int g = (u - 640) * 256 + t;      // [0, 6144)
        int mm = g / 3072, rr = (g % 3072) >> 10, kk = g & 1023;
        float v = (rr == 0) ? p.tk[(size_t)(mm * NK + kk) * 2]
                : (rr == 1) ? p.tk[(size_t)(mm * NK + kk) * 2 + 1] : 1.0f;
        tkx[g] = f2bf1(v);
    } else if (u == 664) {
        for (int g = t; g < 512; g += 256) {
            int hh2 = g >> 5, jj = g & 31;
            w2t[g] = f2h(hh2 < HH ? p.Wk2[jj * HH + hh2] * LOG2E : 0.f);
        }
    } else {
        const int m = u - 665;            // 0..1
        const int c = t & 1, kk = t >> 1;
        float s = 0.f;
        #pragma unroll
        for (int i = 0; i < 8; ++i) s += p.tk[(size_t)(m * NK + kk + i * 128) * 2 + c];
        float* red = (float*)&sTr[0][0];
        red[t] = s; __syncthreads();
        for (int off = 128; off >= 2; off >>= 1) {
            if (t < off) red[t] += red[t + off];
            __syncthreads();
        }
        if (t < 2) ts[m * 2 + t] = red[t];
    }
}

// ============ PHASE 3: attention (1024 blocks x 512 thr, QB=16) =============
__global__ __launch_bounds__(512, 6) void k_phase3(Ptrs p) {
    __shared__ __align__(16) char smem[28928];   // KD0 9344 + KD1 9344 + sP 10240
    const int u = blockIdx.x;
    const int t = threadIdx.x;

    const ushort* qpb = (const ushort*)(p.wsf + QPB_F);
    const ushort* kpb = (const ushort*)(p.wsf + KPB_F);
    const ushort* vpt = (const ushort*)(p.wsf + VPT_F);
    const ushort* aqh = (const ushort*)(p.wsf + AQH_F);
    const ushort* bkh = (const ushort*)(p.wsf + BKH_F);
    const ushort* tkx = (const ushort*)(p.wsf + TKX_F);
    const ushort* w2t = (const ushort*)(p.wsf + W2T_F);
    ushort* part = (ushort*)(p.wsf + PART_F);

    const int ks = u & 7;
    const int qt = (u >> 3) & 63;
    const int m  = u >> 9;
    const int q0 = qt * QB;
    const int kbase = ks * KL;
    const int wid = t >> 6;            // 0..7 = head
    const int l = t & 63;
    const int g = l >> 4;
    const int c16 = l & 15;
    const int h = wid;

    ushort* KD0 = (ushort*)smem;
    ushort* KD1 = (ushort*)(smem + 9344);
    ushort (*sP)[16][40] = (ushort(*)[16][40])(smem + 18688);

    f16x8 w2v = *(const f16x8*)(w2t + c16 * 32 + g * 8);
    const float b2l = (c16 < HH) ? p.bk2[c16] * LOG2E : 0.f;
    const f16x8 zero8 = {0, 0, 0, 0, 0, 0, 0, 0};

    bf16x8 qb = *(const bf16x8*)(qpb + (size_t)(m * NQ + q0 + c16) * HD + h * DD + g * 8);
    f16x8 aqv[2];
    #pragma unroll
    for (int qi = 0; qi < 2; ++qi)
        aqv[qi] = *(const f16x8*)(aqh + (size_t)(m * NQ + q0 + wid * 2 + qi) * KHC + g * 8);

    struct BkOps { f16x8 b0, b1; };
    struct KavOps { bf16x8 ka0, ka1, v0, v1, vt; };
    const size_t vbase = (size_t)m * (HD * NK);
    const size_t tbase = (size_t)m * 3072 + (size_t)(c16 < 2 ? c16 : 2) * NK;

    auto loadBk = [&](int k0) {
        BkOps c;
        c.b0 = *(const f16x8*)(bkh + (size_t)(m * NK + k0 + c16) * KHC + g * 8);
        c.b1 = *(const f16x8*)(bkh + (size_t)(m * NK + k0 + 16 + c16) * KHC + g * 8);
        return c;
    };
    auto loadKav = [&](int k0) {
        KavOps c;
        c.ka0 = *(const bf16x8*)(kpb + (size_t)(m * NK + k0 + c16) * HD + h * DD + g * 8);
        c.ka1 = *(const bf16x8*)(kpb + (size_t)(m * NK + k0 + 16 + c16) * HD + h * DD + g * 8);
        c.v0  = *(const bf16x8*)(vpt + vbase + (size_t)(h * DD + c16) * NK + k0 + g * 8);
        c.v1  = *(const bf16x8*)(vpt + vbase + (size_t)(h * DD + 16 + c16) * NK + k0 + g * 8);
        c.vt  = *(const bf16x8*)(tkx + tbase + k0 + g * 8);
        return c;
    };

    f32x4 oacc[3];
    #pragma unroll
    for (int c = 0; c < 3; ++c) oacc[c] = (f32x4){0.f, 0.f, 0.f, 0.f};

    auto kdPhase = [&](const BkOps& bk, ushort* kdb) {
        __builtin_amdgcn_s_setprio(1);
        #pragma unroll
        for (int qi = 0; qi < 2; ++qi) {
            const int q = wid * 2 + qi;
            #pragma unroll
            for (int kh = 0; kh < 2; ++kh) {
                f16x8 d = aqv[qi] - (kh ? bk.b1 : bk.b0);
                f16x8 hv = __builtin_elementwise_max(d, zero8);
                f32x4 c = {b2l, b2l, b2l, b2l};
                c = MFMA16(hv, w2v, c);
                if (c16 < HH) {
                    uint2 st;
                    st.x = __builtin_bit_cast(uint, __builtin_amdgcn_cvt_pkrtz(c[0], c[1]));
                    st.y = __builtin_bit_cast(uint, __builtin_amdgcn_cvt_pkrtz(c[2], c[3]));
                    *(uint2*)&kdb[c16 * KDH2 + q * KDQ + kh * 16 + g * 4] = st;
                }
            }
        }
        __builtin_amdgcn_s_setprio(0);
    };
    auto qkpv = [&](const KavOps& kv, const ushort* kdbuf) {
        __builtin_amdgcn_s_setprio(1);
        const ushort* kdb = &kdbuf[h * KDH2];
        #pragma unroll
        for (int kf = 0; kf < 2; ++kf) {
            uint2 kd2 = *(const uint2*)&kdb[c16 * KDQ + kf * 16 + g * 4];
            f16x2 k01 = __builtin_bit_cast(f16x2, kd2.x);
            f16x2 k23 = __builtin_bit_cast(f16x2, kd2.y);
            f32x4 cinit = {(float)k01[0], (float)k01[1], (float)k23[0], (float)k23[1]};
            f32x4 s = MFMA((kf ? kv.ka1 : kv.ka0), qb, cinit);
            uint2 pk;
            pk.x = cvt_pk_bf16(EXP2(s[0]), EXP2(s[1]));
            pk.y = cvt_pk_bf16(EXP2(s[2]), EXP2(s[3]));
            *(uint2*)&sP[wid][c16][kf * 16 + g * 4] = pk;
        }
        bf16x8 pa = *(const bf16x8*)&sP[wid][c16][g * 8];
        oacc[0] = MFMA(pa, kv.v0, oacc[0]);
        oacc[1] = MFMA(pa, kv.v1, oacc[1]);
        oacc[2] = MFMA(pa, kv.vt, oacc[2]);
        __builtin_amdgcn_s_setprio(0);
    };

    // ---- software pipeline: one barrier per chunk, dbuf KD ----
    BkOps bk0v = loadBk(kbase);
    KavOps kv0 = loadKav(kbase);
    BkOps bk1v = loadBk(kbase + KB);
    KavOps kv1 = loadKav(kbase + KB);
    kdPhase(bk0v, KD0);
    __syncthreads();

    // CH0: kd(1)->KD1 | qkpv(0)<-KD0
    kdPhase(bk1v, KD1);
    BkOps bk2v = loadBk(kbase + 2 * KB);
    qkpv(kv0, KD0);
    kv0 = loadKav(kbase + 2 * KB);
    __syncthreads();
    // CH1: kd(2)->KD0 | qkpv(1)<-KD1
    kdPhase(bk2v, KD0);
    BkOps bk3v = loadBk(kbase + 3 * KB);
    qkpv(kv1, KD1);
    kv1 = loadKav(kbase + 3 * KB);
    __syncthreads();
    // CH2: kd(3)->KD1 | qkpv(2)<-KD0
    kdPhase(bk3v, KD1);
    qkpv(kv0, KD0);
    __syncthreads();
    // CH3: qkpv(3)<-KD1
    qkpv(kv1, KD1);

    // ---- stage partials into sP (wave-private plane, dead after qkpv) ------
    #pragma unroll
    for (int r = 0; r < 4; ++r) {
        const int q = g * 4 + r;
        ushort* row = &sP[wid][q][0];
        row[c16]      = f2bf1(oacc[0][r]);
        row[16 + c16] = f2bf1(oacc[1][r]);
        float e = oacc[2][r];
        if (c16 < 2) row[32 + c16] = f2bf1(e);
        else if (c16 == 2) *(float*)(row + 34) = e;
    }
    __syncthreads();
    // ---- coalesced cooperative write: 8 planes x 1280 B (80 uint4 each) ----
    for (int idx = t; idx < 640; idx += 512) {
        const int hp = idx / 80, w = idx % 80;
        size_t dstu = ((size_t)((m * HH + hp) * KSPLIT + ks) * NQ + q0) * 40 + (size_t)w * 8;
        *(uint4*)(part + dstu) = *(const uint4*)(&sP[hp][0][0] + w * 8);
    }
}

// ===================== PHASE 4: combine + outproj (256 blocks, 8-q units) ===
__global__ __launch_bounds__(256, 4) void k_phase4(Ptrs p) {
    __shared__ __align__(16) ushort sHob[16][264];   // rows 0..7 valid, 8..15 zeroed
    __shared__ float sD[8][8][2];
    const int u = blockIdx.x;
    const int t = threadIdx.x;
    const ushort* part = (const ushort*)(p.wsf + PART_F);
    const ushort* wt = (const ushort*)(p.wsf + WT_F);
    const float* ts = p.wsf + TS_F;
    float* tq_out = p.out + (size_t)MB * NQ * HD;

    const int m = u >> 7;
    const int q0 = (u & 127) * 8;

    // zero-fill unused sHob rows 8..15 first (uniform, no divergence)
    for (int i = t; i < 8 * 264; i += 256)
        (&sHob[8][0])[i] = 0;

    // ---- combine across ALL 256 threads: each owns an 8-dim quarter --------
    {
        const int h = t >> 5;            // 0..7
        const int dq = (t >> 3) & 3;     // 0..3 (quarter of the 32 O-dims)
        const int qloc = t & 7;
        const int q = q0 + qloc;
        const int mh = m * HH + h;
        float accO[8] = {};
        float aT = 0.f, lsum = 0.f;
        for (int s = 0; s < KSPLIT; ++s) {
            const ushort* ps = part + ((size_t)(mh * KSPLIT + s) * NQ + q) * 40;
            uint4 v0 = *(const uint4*)(ps + dq * 8);
            accO[0] += bf2f(v0.x); accO[1] += bf2f(v0.x >> 16);
            accO[2] += bf2f(v0.y); accO[3] += bf2f(v0.y >> 16);
            accO[4] += bf2f(v0.z); accO[5] += bf2f(v0.z >> 16);
            accO[6] += bf2f(v0.w); accO[7] += bf2f(v0.w >> 16);
            uint at = *(const uint*)(ps + 32);
            aT += bf2f(dq == 0 ? at : (at >> 16));   // valid for dq<2 (comp = dq)
            lsum += *(const float*)(ps + 34);
        }
        const float inv = 1.f / lsum;
        uint dd[4];
        #pragma unroll
        for (int i = 0; i < 4; ++i)
            dd[i] = cvt_pk_bf16(accO[2 * i] * inv, accO[2 * i + 1] * inv);
        *(uint4*)&sHob[qloc][h * DD + dq * 8] = (uint4){dd[0], dd[1], dd[2], dd[3]};
        if (dq < 2) {
            const float A = aT * inv;
            const float tqc = p.tq[(size_t)(m * NQ + q) * 2 + dq];
            sD[h][qloc][dq] = p.Wphi[h * 2 + dq] * (tqc - A);
        }
    }
    __syncthreads();

    if (t < 16) {
        int ql2 = t >> 1, c = t & 1;
        float s = 0.f;
        #pragma unroll
        for (int hh2 = 0; hh2 < 8; ++hh2) s += sD[hh2][ql2][c];
        int qg = q0 + ql2;
        float tqv = p.tq[(size_t)(m * NQ + qg) * 2 + c];
        const float invnk = 1.f / (float)NK;
        tq_out[(size_t)(m * NQ + qg) * 2 + c] =
            tqv + s * invnk + p.bphi[c] * (tqv - ts[m * 2 + c] * invnk);
    }

    // outproj: out[8 x 256] = sHob(rows 0..7) @ Wo^T + bo
    const ushort* wz3 = wt + (size_t)3 * 65536;
    const int wid = t >> 6, l = t & 63, g = l >> 4, c16 = l & 15;
    f32x4 acc[4];
    #pragma unroll
    for (int i = 0; i < 4; ++i) acc[i] = (f32x4){0.f, 0.f, 0.f, 0.f};
    for (int k0 = 0; k0 < HD; k0 += 32) {
        bf16x8 af = *(const bf16x8*)&sHob[c16][k0 + g * 8];
        #pragma unroll
        for (int cf = 0; cf < 4; ++cf) {
            int col = wid * 64 + cf * 16 + c16;
            bf16x8 bf = *(const bf16x8*)(wz3 + (size_t)col * 256 + k0 + g * 8);
            acc[cf] = MFMA(af, bf, acc[cf]);
        }
    }
    if (g < 2) {   // D-rows 0..7 only (rows depend solely on matching A-rows)
        #pragma unroll
        for (int cf = 0; cf < 4; ++cf) {
            int col = wid * 64 + cf * 16 + c16;
            float bv = p.bo[col];
            #pragma unroll
            for (int r = 0; r < 4; ++r) {
                int orow = q0 + g * 4 + r;
                p.out[(size_t)(m * NQ + orow) * DXC + col] = acc[cf][r] + bv;
            }
        }
    }
}

extern "C" void kernel_launch(void* const* d_in, const int* in_sizes, int n_in,
                              void* d_out, int out_size, void* d_ws, size_t ws_size,
                              hipStream_t stream)
{
    Ptrs p;
    p.xq   = (const float*)d_in[0];
    p.xk   = (const float*)d_in[1];
    p.xv   = (const float*)d_in[2];
    p.tq   = (const float*)d_in[3];
    p.tk   = (const float*)d_in[4];
    p.Wq   = (const float*)d_in[5];
    p.Wk   = (const float*)d_in[6];
    p.Wv   = (const float*)d_in[7];
    p.Wo   = (const float*)d_in[8];
    p.bo   = (const float*)d_in[9];
    p.Wk1  = (const float*)d_in[10];
    p.bk1  = (const float*)d_in[11];
    p.Wk2  = (const float*)d_in[12];
    p.bk2  = (const float*)d_in[13];
    p.Wphi = (const float*)d_in[14];
    p.bphi = (const float*)d_in[15];
    p.wsf  = (float*)d_ws;
    p.out  = (float*)d_out;

    hipLaunchKernelGGL(k_wconv,    dim3(64),   dim3(256), 0, stream, p);
    hipLaunchKernelGGL(k_projprep, dim3(667),  dim3(256), 0, stream, p);
    hipLaunchKernelGGL(k_phase3,   dim3(1024), dim3(512), 0, stream, p);
    hipLaunchKernelGGL(k_phase4,   dim3(256),  dim3(256), 0, stream, p);
}

// Round 20
// 54.343 us; speedup vs baseline: 1.3858x; 1.3858x over previous
//
#include <hip/hip_runtime.h>
#include <hip/hip_bf16.h>

#define MB 2
#define NQ 1024
#define NK 1024
#define DXC 256
#define HD 256
#define HH 8
#define DD 32
#define KHC 32
#define LOG2E 1.4426950408889634f
#define QSCALE 0.25503472301046627f   // 32^-0.5 * LOG2E

#define QB 32
#define KB 32
#define KSPLIT 8
#define KL 128
#define NCHUNK 4

// ws layout (float offsets)
#define QPB_F   0u            // bf16 q (scaled QSCALE)  [2][1024][256]
#define KPB_F   262144u       // bf16 k
#define VPT_F   524288u       // bf16 v^T [2][256][1024]
#define WT_F    786432u       // bf16 W^T x4 mats [4][256 col][256 k]
#define AQH_F   917504u       // f16 aq [2][1024][32]
#define BKH_F   950272u       // f16 bk [2][1024][32]
#define TS_F    983040u       // f32 tsum[4] (+pad to 8)
#define TKX_F   983048u       // bf16 [2][3][1024] (tk0,tk1,ones)
#define W2T_F   986120u       // f16 [16][32] Wk2^T*LOG2E
#define PART_F  986376u       // ushort [16mh][8ks][1024q][40]

typedef float f32x4 __attribute__((ext_vector_type(4)));
typedef short bf16x8 __attribute__((ext_vector_type(8)));
typedef _Float16 f16x8 __attribute__((ext_vector_type(8)));
typedef _Float16 f16x2 __attribute__((ext_vector_type(2)));

#define MFMA(a, b, c)   __builtin_amdgcn_mfma_f32_16x16x32_bf16(a, b, c, 0, 0, 0)
#define MFMA16(a, b, c) __builtin_amdgcn_mfma_f32_16x16x32_f16(a, b, c, 0, 0, 0)
#define EXP2(x) exp2f(x)

// sKD geometry: [h][q][k] f16, k-stride 36, plane stride 1160 shorts
#define KDQ 36
#define KDH 1160

struct Ptrs {
    const float *xq, *xk, *xv, *tq, *tk;
    const float *Wq, *Wk, *Wv, *Wo, *bo;
    const float *Wk1, *bk1, *Wk2, *bk2, *Wphi, *bphi;
    float* wsf;
    float* out;
};

__device__ __forceinline__ uint cvt_pk_bf16(float lo, float hi) {
    uint r;
    asm("v_cvt_pk_bf16_f32 %0, %1, %2" : "=v"(r) : "v"(lo), "v"(hi));
    return r;
}
__device__ __forceinline__ ushort f2bf1(float f) { return (ushort)cvt_pk_bf16(f, 0.f); }
__device__ __forceinline__ float bf2f(uint x) {
    return __uint_as_float((x & 0xffffu) << 16);
}
__device__ __forceinline__ ushort f2h(float f) {
    _Float16 h = (_Float16)f;
    return __builtin_bit_cast(ushort, h);
}

// ===================== KERNEL A: wconv (64 blocks) ==========================
__global__ __launch_bounds__(256, 4) void k_wconv(Ptrs p) {
    __shared__ __align__(16) float sW[64][65];
    const int u = blockIdx.x;
    const int t = threadIdx.x;
    ushort* wt = (ushort*)(p.wsf + WT_F);

    const int mat = u >> 4;
    const float* W = (mat == 0) ? p.Wq : (mat == 1) ? p.Wk : (mat == 2) ? p.Wv : p.Wo;
    const int k0 = (u & 3) * 64, c0 = ((u >> 2) & 3) * 64;
    #pragma unroll
    for (int i = 0; i < 4; ++i) {
        int flat = i * 1024 + t * 4;
        int r = flat >> 6, c = flat & 63;
        float4 v4 = *(const float4*)(W + (size_t)(k0 + r) * 256 + c0 + c);
        sW[r][c] = v4.x; sW[r][c + 1] = v4.y; sW[r][c + 2] = v4.z; sW[r][c + 3] = v4.w;
    }
    __syncthreads();
    #pragma unroll
    for (int i = 0; i < 4; ++i) {
        int flat = i * 1024 + t * 4;
        int cc = flat >> 6, kk = flat & 63;
        uint2 pk;
        pk.x = cvt_pk_bf16(sW[kk][cc], sW[kk + 1][cc]);
        pk.y = cvt_pk_bf16(sW[kk + 2][cc], sW[kk + 3][cc]);
        *(uint2*)(wt + (size_t)mat * 65536 + (size_t)(c0 + cc) * 256 + k0 + kk) = pk;
    }
}

// ===================== KERNEL B: projections + prep (667 blocks) ============
__global__ __launch_bounds__(256, 4) void k_projprep(Ptrs p) {
    __shared__ __align__(16) ushort sTr[256][24];
    const int u = blockIdx.x;
    const int t = threadIdx.x;
    ushort* qpb = (ushort*)(p.wsf + QPB_F);
    ushort* kpb = (ushort*)(p.wsf + KPB_F);
    ushort* vpt = (ushort*)(p.wsf + VPT_F);
    const ushort* wt = (const ushort*)(p.wsf + WT_F);
    ushort* aqh = (ushort*)(p.wsf + AQH_F);
    ushort* bkh = (ushort*)(p.wsf + BKH_F);
    ushort* tkx = (ushort*)(p.wsf + TKX_F);
    ushort* w2t = (ushort*)(p.wsf + W2T_F);
    float*  ts  = p.wsf + TS_F;

    if (u < 384) {
        // ---- projections ----
        const int z = u / 128;            // 0=q, 1=k, 2=v
        const int R0 = (u % 128) * 16;    // row in [0, 2048)
        const float* x = (z == 0) ? p.xq : (z == 1) ? p.xk : p.xv;
        const ushort* wz = wt + (size_t)z * 65536;
        const int wid = t >> 6, l = t & 63, g = l >> 4, c16 = l & 15;
        const int wc = wid * 64;
        const int row = R0 + c16;

        f32x4 acc[4];
        #pragma unroll
        for (int i = 0; i < 4; ++i) acc[i] = (f32x4){0.f, 0.f, 0.f, 0.f};

        for (int k0 = 0; k0 < DXC; k0 += 32) {
            const float* xr = x + (size_t)row * DXC + k0 + g * 8;
            float4 a0 = *(const float4*)xr;
            float4 a1 = *(const float4*)(xr + 4);
            union { bf16x8 v; uint d[4]; } af;
            af.d[0] = cvt_pk_bf16(a0.x, a0.y);
            af.d[1] = cvt_pk_bf16(a0.z, a0.w);
            af.d[2] = cvt_pk_bf16(a1.x, a1.y);
            af.d[3] = cvt_pk_bf16(a1.z, a1.w);
            #pragma unroll
            for (int cf = 0; cf < 4; ++cf) {
                bf16x8 bf = *(const bf16x8*)(wz + (size_t)(wc + cf * 16 + c16) * 256 + k0 + g * 8);
                acc[cf] = MFMA(af.v, bf, acc[cf]);
            }
        }
        if (z != 2) {
            #pragma unroll
            for (int cf = 0; cf < 4; ++cf) {
                #pragma unroll
                for (int r = 0; r < 4; ++r) {
                    int orow = R0 + g * 4 + r;
                    int col = wc + cf * 16 + c16;
                    float v = acc[cf][r];
                    if (z == 0) qpb[(size_t)orow * HD + col] = f2bf1(v * QSCALE);
                    else        kpb[(size_t)orow * HD + col] = f2bf1(v);
                }
            }
        } else {
            #pragma unroll
            for (int cf = 0; cf < 4; ++cf)
                #pragma unroll
                for (int r = 0; r < 4; ++r)
                    sTr[wc + cf * 16 + c16][g * 4 + r] = f2bf1(acc[cf][r]);
            __syncthreads();
            const int mq = R0 >> 10, rin = R0 & 1023;
            ushort* dst = vpt + (size_t)mq * (HD * NK) + (size_t)t * NK + rin;
            *(uint4*)dst       = *(const uint4*)&sTr[t][0];
            *(uint4*)(dst + 8) = *(const uint4*)&sTr[t][8];
        }
    } else if (u < 640) {
        int gid = (u - 384) * 256 + t;    // 0..65535
        int row = gid >> 5, j = gid & 31;
        aqh[gid] = f2h(p.tq[row * 2] * p.Wk1[j] + p.tq[row * 2 + 1] * p.Wk1[KHC + j] + p.bk1[j]);
        bkh[gid] = f2h(p.tk[row * 2] * p.Wk1[j] + p.tk[row * 2 + 1] * p.Wk1[KHC + j]);
    } else if (u < 664) {
        int g = (u - 640) * 256 + t;      // [0, 6144)
        int mm = g / 3072, rr = (g % 3072) >> 10, kk = g & 1023;
        float v = (rr == 0) ? p.tk[(size_t)(mm * NK + kk) * 2]
                : (rr == 1) ? p.tk[(size_t)(mm * NK + kk) * 2 + 1] : 1.0f;
        tkx[g] = f2bf1(v);
    } else if (u == 664) {
        for (int g = t; g < 512; g += 256) {
            int hh2 = g >> 5, jj = g & 31;
            w2t[g] = f2h(hh2 < HH ? p.Wk2[jj * HH + hh2] * LOG2E : 0.f);
        }
    } else {
        const int m = u - 665;            // 0..1
        const int c = t & 1, kk = t >> 1;
        float s = 0.f;
        #pragma unroll
        for (int i = 0; i < 8; ++i) s += p.tk[(size_t)(m * NK + kk + i * 128) * 2 + c];
        float* red = (float*)&sTr[0][0];
        red[t] = s; __syncthreads();
        for (int off = 128; off >= 2; off >>= 1) {
            if (t < off) red[t] += red[t + off];
            __syncthreads();
        }
        if (t < 2) ts[m * 2 + t] = red[t];
    }
}

// ===================== PHASE 3: attention (512 blocks x 512 thr, 1 head/wave)
__global__ __launch_bounds__(512, 4) void k_phase3(Ptrs p) {
    __shared__ __align__(16) char smem[57600];   // KD0 18560 + KD1 18560 + sP 20480
    const int u = blockIdx.x;
    const int t = threadIdx.x;

    const ushort* qpb = (const ushort*)(p.wsf + QPB_F);
    const ushort* kpb = (const ushort*)(p.wsf + KPB_F);
    const ushort* vpt = (const ushort*)(p.wsf + VPT_F);
    const ushort* aqh = (const ushort*)(p.wsf + AQH_F);
    const ushort* bkh = (const ushort*)(p.wsf + BKH_F);
    const ushort* tkx = (const ushort*)(p.wsf + TKX_F);
    const ushort* w2t = (const ushort*)(p.wsf + W2T_F);
    ushort* part = (ushort*)(p.wsf + PART_F);

    const int ks = u & 7;
    const int qt = (u >> 3) & 31;
    const int m  = u >> 8;
    const int q0 = qt * QB;
    const int kbase = ks * KL;
    const int wid = t >> 6;            // 0..7 = head
    const int l = t & 63;
    const int g = l >> 4;
    const int c16 = l & 15;
    const int h = wid;

    ushort* KD0 = (ushort*)smem;
    ushort* KD1 = (ushort*)(smem + 18560);
    ushort (*sP)[32][40] = (ushort(*)[32][40])(smem + 37120);

    f16x8 w2v = *(const f16x8*)(w2t + c16 * 32 + g * 8);
    const float b2l = (c16 < HH) ? p.bk2[c16] * LOG2E : 0.f;
    const f16x8 zero8 = {0, 0, 0, 0, 0, 0, 0, 0};

    bf16x8 qb[2];
    #pragma unroll
    for (int qf = 0; qf < 2; ++qf)
        qb[qf] = *(const bf16x8*)(qpb + (size_t)(m * NQ + q0 + qf * 16 + c16) * HD
                                      + h * DD + g * 8);
    f16x8 aqv[4];
    #pragma unroll
    for (int qi = 0; qi < 4; ++qi)
        aqv[qi] = *(const f16x8*)(aqh + (size_t)(m * NQ + q0 + wid * 4 + qi) * KHC + g * 8);

    struct BkOps { f16x8 b0, b1; };
    struct KavOps { bf16x8 ka0, ka1, v0, v1, vt; };
    const size_t vbase = (size_t)m * (HD * NK);
    const size_t tbase = (size_t)m * 3072 + (size_t)(c16 < 2 ? c16 : 2) * NK;

    auto loadBk = [&](int k0) {
        BkOps c;
        c.b0 = *(const f16x8*)(bkh + (size_t)(m * NK + k0 + c16) * KHC + g * 8);
        c.b1 = *(const f16x8*)(bkh + (size_t)(m * NK + k0 + 16 + c16) * KHC + g * 8);
        return c;
    };
    auto loadKav = [&](int k0) {
        KavOps c;
        c.ka0 = *(const bf16x8*)(kpb + (size_t)(m * NK + k0 + c16) * HD + h * DD + g * 8);
        c.ka1 = *(const bf16x8*)(kpb + (size_t)(m * NK + k0 + 16 + c16) * HD + h * DD + g * 8);
        c.v0  = *(const bf16x8*)(vpt + vbase + (size_t)(h * DD + c16) * NK + k0 + g * 8);
        c.v1  = *(const bf16x8*)(vpt + vbase + (size_t)(h * DD + 16 + c16) * NK + k0 + g * 8);
        c.vt  = *(const bf16x8*)(tkx + tbase + k0 + g * 8);
        return c;
    };

    f32x4 oacc[2][3];
    #pragma unroll
    for (int bb = 0; bb < 2; ++bb)
        #pragma unroll
        for (int c = 0; c < 3; ++c)
            oacc[bb][c] = (f32x4){0.f, 0.f, 0.f, 0.f};

    auto kdPhase = [&](const BkOps& bk, ushort* kdb) {
        __builtin_amdgcn_s_setprio(1);
        #pragma unroll
        for (int qi = 0; qi < 4; ++qi) {
            const int q = wid * 4 + qi;
            #pragma unroll
            for (int kh = 0; kh < 2; ++kh) {
                f16x8 d = aqv[qi] - (kh ? bk.b1 : bk.b0);
                f16x8 hv = __builtin_elementwise_max(d, zero8);
                f32x4 c = {b2l, b2l, b2l, b2l};
                c = MFMA16(hv, w2v, c);
                if (c16 < HH) {
                    uint2 st;
                    st.x = __builtin_bit_cast(uint, __builtin_amdgcn_cvt_pkrtz(c[0], c[1]));
                    st.y = __builtin_bit_cast(uint, __builtin_amdgcn_cvt_pkrtz(c[2], c[3]));
                    *(uint2*)&kdb[c16 * KDH + q * KDQ + kh * 16 + g * 4] = st;
                }
            }
        }
        __builtin_amdgcn_s_setprio(0);
    };
    auto qkpv = [&](const KavOps& kv, const ushort* kdbuf) {
        __builtin_amdgcn_s_setprio(1);
        const ushort* kdb = &kdbuf[h * KDH];
        #pragma unroll
        for (int kf = 0; kf < 2; ++kf) {
            #pragma unroll
            for (int qf = 0; qf < 2; ++qf) {
                uint2 kd2 = *(const uint2*)&kdb[(qf * 16 + c16) * KDQ + kf * 16 + g * 4];
                f16x2 k01 = __builtin_bit_cast(f16x2, kd2.x);
                f16x2 k23 = __builtin_bit_cast(f16x2, kd2.y);
                f32x4 cinit = {(float)k01[0], (float)k01[1], (float)k23[0], (float)k23[1]};
                f32x4 s = MFMA((kf ? kv.ka1 : kv.ka0), qb[qf], cinit);
                uint2 pk;
                pk.x = cvt_pk_bf16(EXP2(s[0]), EXP2(s[1]));
                pk.y = cvt_pk_bf16(EXP2(s[2]), EXP2(s[3]));
                *(uint2*)&sP[wid][qf * 16 + c16][kf * 16 + g * 4] = pk;
            }
        }
        #pragma unroll
        for (int qf = 0; qf < 2; ++qf) {
            bf16x8 pa = *(const bf16x8*)&sP[wid][qf * 16 + c16][g * 8];
            oacc[qf][0] = MFMA(pa, kv.v0, oacc[qf][0]);
            oacc[qf][1] = MFMA(pa, kv.v1, oacc[qf][1]);
            oacc[qf][2] = MFMA(pa, kv.vt, oacc[qf][2]);
        }
        __builtin_amdgcn_s_setprio(0);
    };

    // ---- software pipeline: one barrier per chunk, dbuf KD ----
    BkOps bk0v = loadBk(kbase);
    KavOps kv0 = loadKav(kbase);
    BkOps bk1v = loadBk(kbase + KB);
    KavOps kv1 = loadKav(kbase + KB);
    kdPhase(bk0v, KD0);
    __syncthreads();

    // CH0: kd(1)->KD1 | qkpv(0)<-KD0
    kdPhase(bk1v, KD1);
    BkOps bk2v = loadBk(kbase + 2 * KB);
    qkpv(kv0, KD0);
    kv0 = loadKav(kbase + 2 * KB);
    __syncthreads();
    // CH1: kd(2)->KD0 | qkpv(1)<-KD1
    kdPhase(bk2v, KD0);
    BkOps bk3v = loadBk(kbase + 3 * KB);
    qkpv(kv1, KD1);
    kv1 = loadKav(kbase + 3 * KB);
    __syncthreads();
    // CH2: kd(3)->KD1 | qkpv(2)<-KD0
    kdPhase(bk3v, KD1);
    qkpv(kv0, KD0);
    __syncthreads();
    // CH3: qkpv(3)<-KD1
    qkpv(kv1, KD1);

    // ---- stage partials into sP (wave-private plane, dead after qkpv) ------
    #pragma unroll
    for (int qf = 0; qf < 2; ++qf) {
        #pragma unroll
        for (int r = 0; r < 4; ++r) {
            const int q = qf * 16 + g * 4 + r;
            ushort* row = &sP[wid][q][0];
            row[c16]      = f2bf1(oacc[qf][0][r]);
            row[16 + c16] = f2bf1(oacc[qf][1][r]);
            float e = oacc[qf][2][r];
            if (c16 < 2) row[32 + c16] = f2bf1(e);
            else if (c16 == 2) *(float*)(row + 34) = e;
        }
    }
    __syncthreads();
    // ---- coalesced cooperative write: 8 planes x 2560 B (160 uint4 each) ---
    for (int idx = t; idx < 1280; idx += 512) {
        const int hp = idx / 160, w = idx % 160;
        size_t dstu = ((size_t)((m * HH + hp) * KSPLIT + ks) * NQ + q0) * 40 + (size_t)w * 8;
        *(uint4*)(part + dstu) = *(const uint4*)(&sP[hp][0][0] + w * 8);
    }
}

// ===================== PHASE 4: combine + outproj (256 blocks, 8-q units) ===
__global__ __launch_bounds__(256, 4) void k_phase4(Ptrs p) {
    __shared__ __align__(16) ushort sHob[16][264];   // rows 0..7 valid, 8..15 zeroed
    __shared__ float sD[8][8][2];
    const int u = blockIdx.x;
    const int t = threadIdx.x;
    const ushort* part = (const ushort*)(p.wsf + PART_F);
    const ushort* wt = (const ushort*)(p.wsf + WT_F);
    const float* ts = p.wsf + TS_F;
    float* tq_out = p.out + (size_t)MB * NQ * HD;

    const int m = u >> 7;
    const int q0 = (u & 127) * 8;

    // zero-fill unused sHob rows 8..15 first (uniform, no divergence)
    for (int i = t; i < 8 * 264; i += 256)
        (&sHob[8][0])[i] = 0;

    // ---- combine across ALL 256 threads: each owns an 8-dim quarter --------
    {
        const int h = t >> 5;            // 0..7
        const int dq = (t >> 3) & 3;     // 0..3 (quarter of the 32 O-dims)
        const int qloc = t & 7;
        const int q = q0 + qloc;
        const int mh = m * HH + h;
        float accO[8] = {};
        float aT = 0.f, lsum = 0.f;
        for (int s = 0; s < KSPLIT; ++s) {
            const ushort* ps = part + ((size_t)(mh * KSPLIT + s) * NQ + q) * 40;
            uint4 v0 = *(const uint4*)(ps + dq * 8);
            accO[0] += bf2f(v0.x); accO[1] += bf2f(v0.x >> 16);
            accO[2] += bf2f(v0.y); accO[3] += bf2f(v0.y >> 16);
            accO[4] += bf2f(v0.z); accO[5] += bf2f(v0.z >> 16);
            accO[6] += bf2f(v0.w); accO[7] += bf2f(v0.w >> 16);
            uint at = *(const uint*)(ps + 32);
            aT += bf2f(dq == 0 ? at : (at >> 16));   // valid for dq<2 (comp = dq)
            lsum += *(const float*)(ps + 34);
        }
        const float inv = 1.f / lsum;
        uint dd[4];
        #pragma unroll
        for (int i = 0; i < 4; ++i)
            dd[i] = cvt_pk_bf16(accO[2 * i] * inv, accO[2 * i + 1] * inv);
        *(uint4*)&sHob[qloc][h * DD + dq * 8] = (uint4){dd[0], dd[1], dd[2], dd[3]};
        if (dq < 2) {
            const float A = aT * inv;
            const float tqc = p.tq[(size_t)(m * NQ + q) * 2 + dq];
            sD[h][qloc][dq] = p.Wphi[h * 2 + dq] * (tqc - A);
        }
    }
    __syncthreads();

    if (t < 16) {
        int ql2 = t >> 1, c = t & 1;
        float s = 0.f;
        #pragma unroll
        for (int hh2 = 0; hh2 < 8; ++hh2) s += sD[hh2][ql2][c];
        int qg = q0 + ql2;
        float tqv = p.tq[(size_t)(m * NQ + qg) * 2 + c];
        const float invnk = 1.f / (float)NK;
        tq_out[(size_t)(m * NQ + qg) * 2 + c] =
            tqv + s * invnk + p.bphi[c] * (tqv - ts[m * 2 + c] * invnk);
    }

    // outproj: out[8 x 256] = sHob(rows 0..7) @ Wo^T + bo
    const ushort* wz3 = wt + (size_t)3 * 65536;
    const int wid = t >> 6, l = t & 63, g = l >> 4, c16 = l & 15;
    f32x4 acc[4];
    #pragma unroll
    for (int i = 0; i < 4; ++i) acc[i] = (f32x4){0.f, 0.f, 0.f, 0.f};
    for (int k0 = 0; k0 < HD; k0 += 32) {
        bf16x8 af = *(const bf16x8*)&sHob[c16][k0 + g * 8];
        #pragma unroll
        for (int cf = 0; cf < 4; ++cf) {
            int col = wid * 64 + cf * 16 + c16;
            bf16x8 bf = *(const bf16x8*)(wz3 + (size_t)col * 256 + k0 + g * 8);
            acc[cf] = MFMA(af, bf, acc[cf]);
        }
    }
    if (g < 2) {   // D-rows 0..7 only (rows depend solely on matching A-rows)
        #pragma unroll
        for (int cf = 0; cf < 4; ++cf) {
            int col = wid * 64 + cf * 16 + c16;
            float bv = p.bo[col];
            #pragma unroll
            for (int r = 0; r < 4; ++r) {
                int orow = q0 + g * 4 + r;
                p.out[(size_t)(m * NQ + orow) * DXC + col] = acc[cf][r] + bv;
            }
        }
    }
}

extern "C" void kernel_launch(void* const* d_in, const int* in_sizes, int n_in,
                              void* d_out, int out_size, void* d_ws, size_t ws_size,
                              hipStream_t stream)
{
    Ptrs p;
    p.xq   = (const float*)d_in[0];
    p.xk   = (const float*)d_in[1];
    p.xv   = (const float*)d_in[2];
    p.tq   = (const float*)d_in[3];
    p.tk   = (const float*)d_in[4];
    p.Wq   = (const float*)d_in[5];
    p.Wk   = (const float*)d_in[6];
    p.Wv   = (const float*)d_in[7];
    p.Wo   = (const float*)d_in[8];
    p.bo   = (const float*)d_in[9];
    p.Wk1  = (const float*)d_in[10];
    p.bk1  = (const float*)d_in[11];
    p.Wk2  = (const float*)d_in[12];
    p.bk2  = (const float*)d_in[13];
    p.Wphi = (const float*)d_in[14];
    p.bphi = (const float*)d_in[15];
    p.wsf  = (float*)d_ws;
    p.out  = (float*)d_out;

    hipLaunchKernelGGL(k_wconv,    dim3(64),  dim3(256), 0, stream, p);
    hipLaunchKernelGGL(k_projprep, dim3(667), dim3(256), 0, stream, p);
    hipLaunchKernelGGL(k_phase3,   dim3(512), dim3(512), 0, stream, p);
    hipLaunchKernelGGL(k_phase4,   dim3(256), dim3(256), 0, stream, p);
}